// Round 1
// baseline (411.734 us; speedup 1.0000x reference)
//
#include <hip/hip_runtime.h>
#include <hip/hip_bf16.h>

// ---------------------------------------------------------------------------
// UnimodalBranch: conv3x3/s2+bias+relu -> gather -> double CSR segment-max
//                 -> add x_3d
// Strategy:
//   1) zero padded input buffer (halo)
//   2) transpose+convert x [B,Ci,H,W] f32 -> xtp [B,H+2,W+2,Ci] bf16 (padded)
//   3) reorder weights -> wt2 [cout][(kh*3+kw)*64+ci] bf16
//   4) implicit-GEMM conv via mfma_f32_16x16x32_bf16: g[pixel][cout] bf16
//      (bias+relu fused in epilogue)
//   5) fused two-level CSR segment max == max over contiguous row range
//      [a_ptr[v_ptr[n]], a_ptr[v_ptr[n+1]]) since ranges are nested/contiguous
//      and values >= 0 (post-ReLU), empty -> 0. out = x_3d + max.
// ---------------------------------------------------------------------------

#define B_IMG  8
#define C_IN   64
#define H_IN   256
#define W_IN   256
#define C_OUT  128
#define OH     128
#define OW     128
#define NPIX   (B_IMG * OH * OW)     // 131072
#define KTOT   576                   // 64*9
#define M_MAP  800000
#define V_SEG  200000
#define N_PTS  50000

#define HP     258                   // padded H
#define WP     258                   // padded W

typedef __bf16 bf16x8 __attribute__((ext_vector_type(8)));
typedef float  f32x4  __attribute__((ext_vector_type(4)));

typedef unsigned int __attribute__((address_space(3))) u32_lds;
typedef unsigned int __attribute__((address_space(1))) u32_glb;

#define GLOAD_LDS16(gsrc, ldst)                                                \
  __builtin_amdgcn_global_load_lds((const u32_glb*)(gsrc),                     \
                                   (u32_lds*)(ldst), 16, 0, 0)

// ws layout (bytes)
#define XTP_BYTES   (B_IMG * HP * WP * C_IN * 2)          // 68,161,536
#define G_BYTES     (NPIX * C_OUT * 2)                    // 33,554,432
#define XTP_OFF     0
#define G_OFF       XTP_BYTES
#define WT2_OFF     (XTP_BYTES + G_BYTES)

// ---------------------------------------------------------------------------
__global__ __launch_bounds__(256) void zero_ws_kernel(uint4* __restrict__ p, long n16) {
  long i = (long)blockIdx.x * blockDim.x + threadIdx.x;
  long stride = (long)gridDim.x * blockDim.x;
  uint4 z = make_uint4(0u, 0u, 0u, 0u);
  for (; i < n16; i += stride) p[i] = z;
}

// x [B][Ci][H][W] f32 -> xtp [B][HP][WP][Ci] bf16 (interior at +1,+1)
__global__ __launch_bounds__(256) void transpose_x_kernel(
    const float* __restrict__ x, __hip_bfloat16* __restrict__ xtp) {
  __shared__ __hip_bfloat16 tile[64][66];   // stride 66 -> conflict-free col reads
  const int tid = threadIdx.x;
  const int w0  = blockIdx.x * 64;
  const int h   = blockIdx.y;
  const int b   = blockIdx.z;

  const int wl  = tid & 63;
  const int ci4 = tid >> 6;
  for (int cc = 0; cc < 16; ++cc) {
    int ci = cc * 4 + ci4;
    float v = x[(((long)(b * C_IN + ci) * H_IN) + h) * W_IN + w0 + wl];
    tile[ci][wl] = (__hip_bfloat16)v;
  }
  __syncthreads();
  const int cl  = tid & 63;
  const int wo4 = tid >> 6;
  const long dstbase = (((long)(b * HP) + h + 1) * WP + w0 + 1) * C_IN;
  for (int wc = 0; wc < 16; ++wc) {
    int wloc = wc * 4 + wo4;
    xtp[dstbase + (long)wloc * C_IN + cl] = tile[cl][wloc];
  }
}

// w [cout][ci][3][3] f32 -> wt2 [cout][(kh*3+kw)*64+ci] bf16
__global__ __launch_bounds__(256) void wprep_kernel(
    const float* __restrict__ w, __hip_bfloat16* __restrict__ wt2) {
  int tid = blockIdx.x * 256 + threadIdx.x;     // 0 .. 73727
  int cout = tid / KTOT;
  int k    = tid - cout * KTOT;
  int khkw = k >> 6;
  int ci   = k & 63;
  wt2[cout * KTOT + k] = (__hip_bfloat16)w[(cout * C_IN + ci) * 9 + khkw];
}

// ---------------------------------------------------------------------------
// implicit-GEMM conv: C[pixel][cout] over K=576, BK=32 (18 chunks)
// block = 256 thr (4 waves, 2x2 wave grid), tile 128 pixels x 128 cout.
// M-tile = one output row (b, oh, all 128 ow).
// LDS: A[128][32], B(=wt2 rows)[128][32], both double-buffered, XOR swizzled.
__global__ __launch_bounds__(256) void conv_gemm_kernel(
    const __hip_bfloat16* __restrict__ xtp,
    const __hip_bfloat16* __restrict__ wt2,
    const float* __restrict__ bias,
    __hip_bfloat16* __restrict__ g) {
  __shared__ __hip_bfloat16 Abuf[2][128 * 32];
  __shared__ __hip_bfloat16 Bbuf[2][128 * 32];

  const int tid  = threadIdx.x;
  const int lane = tid & 63;
  const int wid  = tid >> 6;
  const int bid  = blockIdx.x;          // 0..1023
  const int bimg = bid >> 7;
  const int oh   = bid & 127;
  const int wr   = wid >> 1;            // wave row (0..1)
  const int wc   = wid & 1;             // wave col (0..1)

  f32x4 acc[4][4] = {};

  // stage A chunk t into Abuf[buf]: rows = ow (0..127), cols = 32 k-vals
  auto stageA = [&](int buf, int t) {
    const int khkw = t >> 1;            // 0..8
    const int ci0  = (t & 1) << 5;      // 0 or 32
    const int kh   = khkw / 3;
    const int kw   = khkw - kh * 3;
    const long rowbase = ((long)(bimg * HP) + (2 * oh + kh)) * WP;
    for (int p = 0; p < 2; ++p) {
      int flat = p * 256 + tid;
      int row  = flat >> 2;                          // pixel ow
      int c    = (flat & 3) ^ ((row >> 1) & 3);      // swizzled 16B chunk
      const __hip_bfloat16* src =
          xtp + (rowbase + (2 * row + kw)) * C_IN + ci0 + c * 8;
      char* dst = (char*)&Abuf[buf][0] + (p * 256 + (wid << 6)) * 16;
      GLOAD_LDS16(src, dst);
    }
  };
  // stage B chunk t: rows = cout (0..127), cols = 32 k-vals
  auto stageB = [&](int buf, int t) {
    const int k0 = t << 5;
    for (int p = 0; p < 2; ++p) {
      int flat = p * 256 + tid;
      int row  = flat >> 2;                          // cout
      int c    = (flat & 3) ^ ((row >> 1) & 3);
      const __hip_bfloat16* src = wt2 + row * KTOT + k0 + c * 8;
      char* dst = (char*)&Bbuf[buf][0] + (p * 256 + (wid << 6)) * 16;
      GLOAD_LDS16(src, dst);
    }
  };

  auto compute = [&](int buf) {
    bf16x8 af[4], bfv[4];
    const int r15 = lane & 15;
    const int kg  = lane >> 4;
    for (int i = 0; i < 4; ++i) {
      int rowa = wr * 64 + i * 16 + r15;
      int cha  = kg ^ ((rowa >> 1) & 3);
      af[i] = *(const bf16x8*)((const char*)&Abuf[buf][0] + rowa * 64 + cha * 16);
      int rowb = wc * 64 + i * 16 + r15;
      int chb  = kg ^ ((rowb >> 1) & 3);
      bfv[i] = *(const bf16x8*)((const char*)&Bbuf[buf][0] + rowb * 64 + chb * 16);
    }
    for (int i = 0; i < 4; ++i)
      for (int n = 0; n < 4; ++n)
        acc[i][n] = __builtin_amdgcn_mfma_f32_16x16x32_bf16(af[i], bfv[n],
                                                            acc[i][n], 0, 0, 0);
  };

  stageA(0, 0);
  stageB(0, 0);
  __syncthreads();
  int cur = 0;
  for (int t = 0; t < 18; ++t) {
    if (t + 1 < 18) { stageA(cur ^ 1, t + 1); stageB(cur ^ 1, t + 1); }
    compute(cur);
    __syncthreads();
    cur ^= 1;
  }

  // epilogue: bias + relu, write bf16 g[pixel][cout]
  const long pixbase = (long)bid * 128;
  const int col0 = wc * 64 + (lane & 15);
  float bn[4];
  for (int n = 0; n < 4; ++n) bn[n] = bias[col0 + n * 16];
  for (int i = 0; i < 4; ++i) {
    int row0 = wr * 64 + i * 16 + (lane >> 4) * 4;
    for (int n = 0; n < 4; ++n) {
      int cout = col0 + n * 16;
      for (int r = 0; r < 4; ++r) {
        float v = acc[i][n][r] + bn[n];
        v = fmaxf(v, 0.0f);
        g[(pixbase + row0 + r) * C_OUT + cout] = (__hip_bfloat16)v;
      }
    }
  }
}

// ---------------------------------------------------------------------------
// fused two-level CSR segment-max + add.
// one wave per point n; lane covers channels {2*lane, 2*lane+1}.
__global__ __launch_bounds__(256) void gather_max_add_kernel(
    const __hip_bfloat16* __restrict__ g,
    const float* __restrict__ x3d,
    const int* __restrict__ fm_idx,
    const int* __restrict__ a_ptr,
    const int* __restrict__ v_ptr,
    float* __restrict__ out) {
  const int tid  = threadIdx.x;
  const int lane = tid & 63;
  const int n    = blockIdx.x * 4 + (tid >> 6);   // wave-uniform

  const int v0 = v_ptr[n];
  const int v1 = v_ptr[n + 1];
  const int r0 = a_ptr[v0];
  const int r1 = a_ptr[v1];

  float m0 = 0.0f, m1 = 0.0f;
  const unsigned* gp = (const unsigned*)g;
  for (int r = r0; r < r1; ++r) {
    int idx = fm_idx[r];
    unsigned u = gp[(long)idx * 64 + lane];
    float f0 = __uint_as_float(u << 16);
    float f1 = __uint_as_float(u & 0xffff0000u);
    m0 = fmaxf(m0, f0);
    m1 = fmaxf(m1, f1);
  }
  const float2 xv = ((const float2*)x3d)[(long)n * 64 + lane];
  float2 o;
  o.x = xv.x + m0;
  o.y = xv.y + m1;
  ((float2*)out)[(long)n * 64 + lane] = o;
}

// ---------------------------------------------------------------------------
extern "C" void kernel_launch(void* const* d_in, const int* in_sizes, int n_in,
                              void* d_out, int out_size, void* d_ws, size_t ws_size,
                              hipStream_t stream) {
  const float* x     = (const float*)d_in[0];
  const float* w     = (const float*)d_in[1];
  const float* bias  = (const float*)d_in[2];
  const float* x3d   = (const float*)d_in[3];
  const int*   fmidx = (const int*)d_in[4];
  const int*   aptr  = (const int*)d_in[5];
  const int*   vptr  = (const int*)d_in[6];
  float* out = (float*)d_out;

  char* ws = (char*)d_ws;
  __hip_bfloat16* xtp = (__hip_bfloat16*)(ws + XTP_OFF);
  __hip_bfloat16* g   = (__hip_bfloat16*)(ws + G_OFF);
  __hip_bfloat16* wt2 = (__hip_bfloat16*)(ws + WT2_OFF);

  // 1) zero padded input (halo must be 0; ws is poisoned each call)
  long n16 = XTP_BYTES / 16;
  hipLaunchKernelGGL(zero_ws_kernel, dim3(4096), dim3(256), 0, stream,
                     (uint4*)xtp, n16);

  // 2) transpose/convert x
  hipLaunchKernelGGL(transpose_x_kernel, dim3(W_IN / 64, H_IN, B_IMG), dim3(256),
                     0, stream, x, xtp);

  // 3) weight reorder
  hipLaunchKernelGGL(wprep_kernel, dim3((C_OUT * KTOT) / 256), dim3(256), 0,
                     stream, w, wt2);

  // 4) conv as implicit GEMM (bias+relu fused)
  hipLaunchKernelGGL(conv_gemm_kernel, dim3(NPIX / 128), dim3(256), 0, stream,
                     xtp, wt2, bias, g);

  // 5) fused double segment-max + add
  hipLaunchKernelGGL(gather_max_add_kernel, dim3(N_PTS / 4), dim3(256), 0,
                     stream, g, x3d, fmidx, aptr, vptr, out);
}

// Round 3
// 304.421 us; speedup vs baseline: 1.3525x; 1.3525x over previous
//
#include <hip/hip_runtime.h>
#include <hip/hip_bf16.h>

// ---------------------------------------------------------------------------
// UnimodalBranch: conv3x3/s2+bias+relu -> gather -> double CSR segment-max
//                 -> add x_3d
//   1) zero padded input buffer (halo)
//   2) transpose+convert x -> xtp [B][258][2 planes][129][64] bf16
//      (even/odd padded-column planes => contiguous A K-chunks)
//   3) reorder weights -> wt2b [khkw][cout][ci] bf16 (contiguous B K-chunks)
//   4) implicit-GEMM conv, mfma_f32_16x16x32_bf16, 128x128 tile, BK=64,
//      XOR-swizzled LDS, global_load_lds w16, dbuf; bias+relu fused;
//      epilogue via LDS for coalesced dwordx4 g stores.
//   5) fused two-level CSR segment max: max over contiguous row range
//      [a_ptr[v_ptr[n]], a_ptr[v_ptr[n+1]]) (values >= 0, empty -> 0),
//      batched-index + 4-rows-per-load gather for ILP. out = x_3d + max.
// ---------------------------------------------------------------------------

#define B_IMG  8
#define C_IN   64
#define H_IN   256
#define W_IN   256
#define C_OUT  128
#define OH     128
#define OW     128
#define NPIX   (B_IMG * OH * OW)     // 131072
#define KTOT   576                   // 64*9
#define N_PTS  50000

#define HP     258                   // padded H rows (ph = h+1)
#define PLANE  (129 * 64)            // 8256 elems: one even/odd column plane
#define HROW   (2 * PLANE)           // 16512 elems per padded row

typedef __bf16 bf16x8 __attribute__((ext_vector_type(8)));
typedef float  f32x4  __attribute__((ext_vector_type(4)));

typedef unsigned int __attribute__((address_space(3))) u32_lds;
typedef unsigned int __attribute__((address_space(1))) u32_glb;

#define GLOAD_LDS16(gsrc, ldst)                                                \
  __builtin_amdgcn_global_load_lds((const u32_glb*)(gsrc),                     \
                                   (u32_lds*)(ldst), 16, 0, 0)

// ws layout (bytes)
#define XTP_BYTES   (B_IMG * HP * HROW * 2)               // 68,161,536
#define G_BYTES     (NPIX * C_OUT * 2)                    // 33,554,432
#define XTP_OFF     0
#define G_OFF       XTP_BYTES
#define WT2_OFF     (XTP_BYTES + G_BYTES)

// ---------------------------------------------------------------------------
__global__ __launch_bounds__(256) void zero_ws_kernel(uint4* __restrict__ p, long n16) {
  long i = (long)blockIdx.x * blockDim.x + threadIdx.x;
  long stride = (long)gridDim.x * blockDim.x;
  uint4 z = make_uint4(0u, 0u, 0u, 0u);
  for (; i < n16; i += stride) p[i] = z;
}

// x [B][Ci][H][W] f32 -> xtp [B][258][2][129][64] bf16 (pc = w+1; plane pc&1)
__global__ __launch_bounds__(256) void transpose_x_kernel(
    const float* __restrict__ x, __hip_bfloat16* __restrict__ xtp) {
  __shared__ __hip_bfloat16 tile[64][66];
  const int tid = threadIdx.x;
  const int w0  = blockIdx.x * 64;
  const int h   = blockIdx.y;
  const int b   = blockIdx.z;

  const int wl  = tid & 63;
  const int ci4 = tid >> 6;
  for (int cc = 0; cc < 16; ++cc) {
    int ci = cc * 4 + ci4;
    float v = x[(((long)(b * C_IN + ci) * H_IN) + h) * W_IN + w0 + wl];
    tile[ci][wl] = (__hip_bfloat16)v;
  }
  __syncthreads();
  const int cl  = tid & 63;
  const int wo4 = tid >> 6;
  const long rowbase = ((long)(b * HP) + h + 1) * HROW;
  for (int wc = 0; wc < 16; ++wc) {
    int wloc = wc * 4 + wo4;
    int pc   = w0 + wloc + 1;
    xtp[rowbase + (pc & 1) * PLANE + (pc >> 1) * 64 + cl] = tile[cl][wloc];
  }
}

// w [cout][ci][3][3] f32 -> wt2b [khkw][cout][ci] bf16
__global__ __launch_bounds__(256) void wprep_kernel(
    const float* __restrict__ w, __hip_bfloat16* __restrict__ wt2b) {
  int tid  = blockIdx.x * 256 + threadIdx.x;   // 0 .. 73727
  int khkw = tid >> 13;
  int cout = (tid >> 6) & 127;
  int ci   = tid & 63;
  wt2b[tid] = (__hip_bfloat16)w[(cout * C_IN + ci) * 9 + khkw];
}

// ---------------------------------------------------------------------------
// implicit-GEMM conv: tile 128 pixels x 128 cout, K=576, BK=64 (9 chunks).
// block = 256 thr (4 waves, 2x2), LDS A/B 16KB each double-buffered (64KB).
// Chunk sources are fully contiguous 16KB; XOR chunk-swizzle (c ^= row&7)
// applied via pre-swizzled global source + swizzled ds_read (rule #21).
__global__ __launch_bounds__(256) void conv_gemm_kernel(
    const __hip_bfloat16* __restrict__ xtp,
    const __hip_bfloat16* __restrict__ wt2b,
    const float* __restrict__ bias,
    __hip_bfloat16* __restrict__ g) {
  __shared__ __hip_bfloat16 Abuf[2][8192];
  __shared__ __hip_bfloat16 Bbuf[2][8192];

  const int tid  = threadIdx.x;
  const int lane = tid & 63;
  const int wid  = tid >> 6;
  const int bid  = blockIdx.x;          // 0..1023 = bimg*128 + oh
  const int bimg = bid >> 7;
  const int oh   = bid & 127;
  const int wr   = wid >> 1;
  const int wc   = wid & 1;

  f32x4 acc[4][4] = {};

  auto stage = [&](int buf, int t) {
    const int kh = t / 3;
    const int kw = t - kh * 3;
    const long abase = (((long)bimg * HP + (2 * oh + kh)) * 2 + (kw & 1)) * PLANE
                       + ((kw == 2) ? 64 : 0);
    const long bbase = (long)t * 8192;
    for (int p = 0; p < 4; ++p) {
      int flat = p * 256 + tid;
      int row  = flat >> 3;                       // 0..127
      int cs   = (flat & 7) ^ (row & 7);          // inverse-swizzled src chunk
      long soff = (long)row * 64 + cs * 8;
      char* dA = (char*)&Abuf[buf][0] + flat * 16;
      char* dB = (char*)&Bbuf[buf][0] + flat * 16;
      GLOAD_LDS16(xtp + abase + soff, dA);
      GLOAD_LDS16(wt2b + bbase + soff, dB);
    }
  };

  auto compute = [&](int buf) {
    const int r15 = lane & 15;
    const int kg  = lane >> 4;
    for (int h = 0; h < 2; ++h) {
      bf16x8 af[4], bfv[4];
      const int co = h * 4 + kg;
      for (int i = 0; i < 4; ++i) {
        int rowa = wr * 64 + i * 16 + r15;
        int ca   = co ^ (rowa & 7);
        af[i] = *(const bf16x8*)((const char*)&Abuf[buf][0] + rowa * 128 + ca * 16);
        int rowb = wc * 64 + i * 16 + r15;
        int cb   = co ^ (rowb & 7);
        bfv[i] = *(const bf16x8*)((const char*)&Bbuf[buf][0] + rowb * 128 + cb * 16);
      }
      for (int i = 0; i < 4; ++i)
        for (int n = 0; n < 4; ++n)
          acc[i][n] = __builtin_amdgcn_mfma_f32_16x16x32_bf16(af[i], bfv[n],
                                                              acc[i][n], 0, 0, 0);
    }
  };

  stage(0, 0);
  __syncthreads();
  int cur = 0;
  for (int t = 0; t < 9; ++t) {
    if (t + 1 < 9) stage(cur ^ 1, t + 1);
    compute(cur);
    __syncthreads();
    cur ^= 1;
  }

  // epilogue: bias+relu -> LDS bf16 C-tile -> coalesced dwordx4 stores
  __hip_bfloat16* ct = &Abuf[0][0];               // 32KB = both A buffers
  const int col0 = wc * 64 + (lane & 15);
  float bn[4];
  for (int n = 0; n < 4; ++n) bn[n] = bias[col0 + n * 16];
  for (int i = 0; i < 4; ++i) {
    int row0 = wr * 64 + i * 16 + (lane >> 4) * 4;
    for (int n = 0; n < 4; ++n) {
      int cout = col0 + n * 16;
      for (int r = 0; r < 4; ++r) {
        float v = fmaxf(acc[i][n][r] + bn[n], 0.0f);
        ct[(row0 + r) * 128 + cout] = (__hip_bfloat16)v;
      }
    }
  }
  __syncthreads();
  const long gbase = (long)bid * (128 * 128);
  for (int it = 0; it < 8; ++it) {
    int flat = it * 256 + tid;
    bf16x8 v = *(const bf16x8*)((const char*)ct + flat * 16);
    *(bf16x8*)(g + gbase + (long)flat * 8) = v;
  }
}

// ---------------------------------------------------------------------------
// fused two-level CSR segment-max + add, ILP version.
// one wave per point n. Batch-load 64 indices coalesced; each lane reads
// 16B (8 channels) so one load covers 4 rows; 2 quads in flight per iter.
__global__ __launch_bounds__(256) void gather_max_add_kernel(
    const __hip_bfloat16* __restrict__ g,
    const float* __restrict__ x3d,
    const int* __restrict__ fm_idx,
    const int* __restrict__ a_ptr,
    const int* __restrict__ v_ptr,
    float* __restrict__ out) {
  const int lane = threadIdx.x & 63;
  const int n    = blockIdx.x * 4 + (threadIdx.x >> 6);

  const int v0 = v_ptr[n];
  const int v1 = v_ptr[n + 1];
  const int r0 = a_ptr[v0];
  const int r1 = a_ptr[v1];
  const int len = r1 - r0;

  const int sub  = lane >> 4;     // row-in-quad 0..3
  const int ch16 = lane & 15;     // 16B chunk = channels ch16*8 .. +7

  float m[8];
#pragma unroll
  for (int k = 0; k < 8; ++k) m[k] = 0.0f;

  const uint4* gp = (const uint4*)g;

  for (int base = 0; base < len; base += 64) {
    int nb = len - base;
    if (nb > 64) nb = 64;
    int li = base + lane;
    if (li >= len) li = len - 1;
    const int idx_l = fm_idx[r0 + li];           // one coalesced batch load

    for (int j = 0; j < nb; j += 8) {
      int ra = j + sub;
      int rb = j + 4 + sub;
      if (ra >= nb) ra = nb - 1;                 // duplicate row: max-safe
      if (rb >= nb) rb = nb - 1;
      int ia = __shfl(idx_l, ra);
      int ib = __shfl(idx_l, rb);
      uint4 va = gp[(long)ia * 16 + ch16];
      uint4 vb = gp[(long)ib * 16 + ch16];
      const unsigned* ua = (const unsigned*)&va;
      const unsigned* ub = (const unsigned*)&vb;
#pragma unroll
      for (int w = 0; w < 4; ++w) {
        m[2 * w]     = fmaxf(m[2 * w],     __uint_as_float(ua[w] << 16));
        m[2 * w + 1] = fmaxf(m[2 * w + 1], __uint_as_float(ua[w] & 0xffff0000u));
        m[2 * w]     = fmaxf(m[2 * w],     __uint_as_float(ub[w] << 16));
        m[2 * w + 1] = fmaxf(m[2 * w + 1], __uint_as_float(ub[w] & 0xffff0000u));
      }
    }
  }

  // combine the 4 row-subgroups (same channels live at lane^16, lane^32)
#pragma unroll
  for (int k = 0; k < 8; ++k) {
    m[k] = fmaxf(m[k], __shfl_xor(m[k], 16));
    m[k] = fmaxf(m[k], __shfl_xor(m[k], 32));
  }

  if (sub == 0) {
    const float4* x4 = (const float4*)x3d;
    float4* o4 = (float4*)out;
    long b0 = (long)n * 32 + ch16 * 2;
    float4 xa = x4[b0];
    float4 xb = x4[b0 + 1];
    float4 oa, ob;
    oa.x = xa.x + m[0]; oa.y = xa.y + m[1]; oa.z = xa.z + m[2]; oa.w = xa.w + m[3];
    ob.x = xb.x + m[4]; ob.y = xb.y + m[5]; ob.z = xb.z + m[6]; ob.w = xb.w + m[7];
    o4[b0]     = oa;
    o4[b0 + 1] = ob;
  }
}

// ---------------------------------------------------------------------------
extern "C" void kernel_launch(void* const* d_in, const int* in_sizes, int n_in,
                              void* d_out, int out_size, void* d_ws, size_t ws_size,
                              hipStream_t stream) {
  const float* x     = (const float*)d_in[0];
  const float* w     = (const float*)d_in[1];
  const float* bias  = (const float*)d_in[2];
  const float* x3d   = (const float*)d_in[3];
  const int*   fmidx = (const int*)d_in[4];
  const int*   aptr  = (const int*)d_in[5];
  const int*   vptr  = (const int*)d_in[6];
  float* out = (float*)d_out;

  char* ws = (char*)d_ws;
  __hip_bfloat16* xtp  = (__hip_bfloat16*)(ws + XTP_OFF);
  __hip_bfloat16* g    = (__hip_bfloat16*)(ws + G_OFF);
  __hip_bfloat16* wt2b = (__hip_bfloat16*)(ws + WT2_OFF);

  long n16 = XTP_BYTES / 16;
  hipLaunchKernelGGL(zero_ws_kernel, dim3(4096), dim3(256), 0, stream,
                     (uint4*)xtp, n16);
  hipLaunchKernelGGL(transpose_x_kernel, dim3(W_IN / 64, H_IN, B_IMG), dim3(256),
                     0, stream, x, xtp);
  hipLaunchKernelGGL(wprep_kernel, dim3((C_OUT * KTOT) / 256), dim3(256), 0,
                     stream, w, wt2b);
  hipLaunchKernelGGL(conv_gemm_kernel, dim3(NPIX / 128), dim3(256), 0, stream,
                     xtp, wt2b, bias, g);
  hipLaunchKernelGGL(gather_max_add_kernel, dim3(N_PTS / 4), dim3(256), 0,
                     stream, g, x3d, fmidx, aptr, vptr, out);
}